// Round 1
// baseline (1766.497 us; speedup 1.0000x reference)
//
#include <hip/hip_runtime.h>
#include <math.h>

#define BB 8
#define TT 4096
#define NE 512
#define DD 64
#define TQ 4   // q rows per block (1 wave each)

// ---------------- Projection: Q = x@wq, K = x@wk (V==K per reference bug) ----
// Block: 256 threads computes a 64-row x 64-col tile of BOTH Q and K,
// staging x / wq / wk chunks in LDS. grid = 32768/64 = 512 blocks.
__global__ __launch_bounds__(256) void proj_kernel(
    const float* __restrict__ x, const float* __restrict__ wq,
    const float* __restrict__ wk, float* __restrict__ Qo, float* __restrict__ Ko) {
  __shared__ float xs[64][64];
  __shared__ float wqs[64][64];
  __shared__ float wks[64][64];
  const int t = threadIdx.x;
  const size_t rbase = (size_t)blockIdx.x * 64;
  const int c  = t & 63;   // output col
  const int rg = t >> 6;   // row group 0..3 (16 rows each)

  float accq[16], acck[16];
#pragma unroll
  for (int i = 0; i < 16; ++i) { accq[i] = 0.f; acck[i] = 0.f; }

  for (int nb = 0; nb < NE; nb += 64) {
    __syncthreads();
    // stage tiles: 4096 floats each = 1024 float4, 256 threads x 4
#pragma unroll
    for (int i = 0; i < 4; ++i) {
      int f = t + i * 256;            // float4 index 0..1023
      int row = f >> 4;               // 0..63
      int co  = (f & 15) * 4;         // 0,4,...,60
      const float4 xv = *(const float4*)&x[(rbase + row) * NE + nb + co];
      *(float4*)&xs[row][co] = xv;
      const float4 qv = *(const float4*)&wq[(size_t)(nb + row) * DD + co];
      *(float4*)&wqs[row][co] = qv;
      const float4 kv = *(const float4*)&wk[(size_t)(nb + row) * DD + co];
      *(float4*)&wks[row][co] = kv;
    }
    __syncthreads();
#pragma unroll 16
    for (int n = 0; n < 64; ++n) {
      const float aq = wqs[n][c];
      const float ak = wks[n][c];
#pragma unroll
      for (int r = 0; r < 16; ++r) {
        const float xv = xs[rg * 16 + r][n];
        accq[r] = fmaf(xv, aq, accq[r]);
        acck[r] = fmaf(xv, ak, acck[r]);
      }
    }
  }
#pragma unroll
  for (int r = 0; r < 16; ++r) {
    const size_t row = rbase + rg * 16 + r;
    Qo[row * DD + c] = accq[r];
    Ko[row * DD + c] = acck[r];
  }
}

// ---------------- Flash-style causal attention, fp32 -------------------------
// 1 wave per q row, TQ=4 rows per 256-thread block (share K LDS staging).
// K chunk staged TRANSPOSED with +1 pad: kt[d][k], stride 65 -> conflict-free
// for both score phase (lane=k) and PV phase (lane=d). V == K.
__global__ __launch_bounds__(256) void attn_kernel(
    const float* __restrict__ Q, const float* __restrict__ K,
    float* __restrict__ O) {
  __shared__ float kt[64][65];
  __shared__ float qs[TQ][64];
  const int blk  = blockIdx.x;
  const int b    = blk / (TT / TQ);
  const int qt   = blk % (TT / TQ);
  const int wave = threadIdx.x >> 6;
  const int lane = threadIdx.x & 63;
  const int qrow = qt * TQ + wave;
  const float* Qb = Q + (size_t)b * TT * DD;
  const float* Kb = K + (size_t)b * TT * DD;

  // stage the TQ query rows
  qs[wave][lane] = Qb[(size_t)qrow * DD + lane];

  float m = -INFINITY, l = 0.f, acc = 0.f;
  const int qmax = qt * TQ + (TQ - 1);
  const int nchunk = qmax / 64 + 1;
  const float scale = 0.125f;  // 1/sqrt(64)

  for (int ch = 0; ch < nchunk; ++ch) {
    const int kb = ch * 64;
    __syncthreads();
    // stage 64 keys x 64 dims, transposed
#pragma unroll
    for (int i = 0; i < 16; ++i) {
      const int f = threadIdx.x + i * 256;  // 0..4095
      const int kk = f >> 6;
      const int d  = f & 63;
      kt[d][kk] = Kb[(size_t)(kb + kk) * DD + d];
    }
    __syncthreads();

    // ---- score: lane = key index
    float s = 0.f;
#pragma unroll
    for (int d = 0; d < 64; ++d) s = fmaf(qs[wave][d], kt[d][lane], s);
    s *= scale;
    const bool valid = (kb + lane) <= qrow;
    s = valid ? s : -INFINITY;

    float mx = s;
#pragma unroll
    for (int off = 32; off > 0; off >>= 1) mx = fmaxf(mx, __shfl_xor(mx, off));
    const float mnew = fmaxf(m, mx);
    const float p = valid ? __expf(s - mnew) : 0.f;
    const float corr = (m == -INFINITY) ? 0.f : __expf(m - mnew);
    float psum = p;
#pragma unroll
    for (int off = 32; off > 0; off >>= 1) psum += __shfl_xor(psum, off);
    l = l * corr + psum;
    acc *= corr;
    m = mnew;

    // ---- PV: lane = output dim d; V == K
#pragma unroll
    for (int kk = 0; kk < 64; ++kk) {
      const float pk = __shfl(p, kk);
      acc = fmaf(pk, kt[lane][kk], acc);
    }
  }
  O[((size_t)b * TT + qrow) * DD + lane] = acc / l;
}

extern "C" void kernel_launch(void* const* d_in, const int* in_sizes, int n_in,
                              void* d_out, int out_size, void* d_ws, size_t ws_size,
                              hipStream_t stream) {
  const float* x  = (const float*)d_in[0];
  const float* wq = (const float*)d_in[1];
  const float* wk = (const float*)d_in[2];
  // d_in[3] (w_v) intentionally unused: reference computes v with w_k.
  float* out = (float*)d_out;

  const size_t rows = (size_t)BB * TT;      // 32768
  float* Qbuf = (float*)d_ws;
  float* Kbuf = Qbuf + rows * DD;           // 8MB each, 16MB total

  proj_kernel<<<dim3(rows / 64), dim3(256), 0, stream>>>(x, wq, wk, Qbuf, Kbuf);
  attn_kernel<<<dim3(BB * TT / TQ), dim3(256), 0, stream>>>(Qbuf, Kbuf, out);
}

// Round 2
// 245.777 us; speedup vs baseline: 7.1874x; 7.1874x over previous
//
#include <hip/hip_runtime.h>
#include <math.h>

#define BB 8
#define TT 4096
#define NE 512
#define DD 64

using f32x4 = __attribute__((ext_vector_type(4))) float;
using s16x8 = __attribute__((ext_vector_type(8))) short;

__device__ __forceinline__ ushort f2bf(float f) {
  uint u = __builtin_bit_cast(uint, f);
  u += 0x7fffu + ((u >> 16) & 1u);
  return (ushort)(u >> 16);
}

// ---------------- Projection: Q = (x@wq)*0.125 -> bf16, K = x@wk -> bf16 -----
__global__ __launch_bounds__(256) void proj_kernel(
    const float* __restrict__ x, const float* __restrict__ wq,
    const float* __restrict__ wk, ushort* __restrict__ Qo, ushort* __restrict__ Ko) {
  __shared__ float xs[64][64];
  __shared__ float wqs[64][64];
  __shared__ float wks[64][64];
  const int t = threadIdx.x;
  const size_t rbase = (size_t)blockIdx.x * 64;
  const int c  = t & 63;
  const int rg = t >> 6;

  float accq[16], acck[16];
#pragma unroll
  for (int i = 0; i < 16; ++i) { accq[i] = 0.f; acck[i] = 0.f; }

  for (int nb = 0; nb < NE; nb += 64) {
    __syncthreads();
#pragma unroll
    for (int i = 0; i < 4; ++i) {
      int f = t + i * 256;
      int row = f >> 4;
      int co  = (f & 15) * 4;
      *(float4*)&xs[row][co]  = *(const float4*)&x[(rbase + row) * NE + nb + co];
      *(float4*)&wqs[row][co] = *(const float4*)&wq[(size_t)(nb + row) * DD + co];
      *(float4*)&wks[row][co] = *(const float4*)&wk[(size_t)(nb + row) * DD + co];
    }
    __syncthreads();
#pragma unroll 16
    for (int n = 0; n < 64; ++n) {
      const float aq = wqs[n][c];
      const float ak = wks[n][c];
#pragma unroll
      for (int r = 0; r < 16; ++r) {
        const float xv = xs[rg * 16 + r][n];
        accq[r] = fmaf(xv, aq, accq[r]);
        acck[r] = fmaf(xv, ak, acck[r]);
      }
    }
  }
#pragma unroll
  for (int r = 0; r < 16; ++r) {
    const size_t row = rbase + rg * 16 + r;
    Qo[row * DD + c] = f2bf(accq[r] * 0.125f);  // fold 1/sqrt(64) into Q
    Ko[row * DD + c] = f2bf(acck[r]);
  }
}

// ---------------- MFMA flash attention (bf16), V == K ------------------------
// Block: 4 waves x 16 q-rows = 64-row q-tile. Processes tile pair (p, 63-p)
// sequentially -> exactly 65 chunks per block (load-balanced). Grid = 8*32.
// S^T = mfma(K, Q); softmax lane-local per q; P -> LDS bf16; O^T = mfma(K^T, P^T).
__global__ __launch_bounds__(256) void attn_kernel(
    const ushort* __restrict__ Qg, const ushort* __restrict__ Kg,
    float* __restrict__ O) {
  __shared__ __align__(16) char smem[24576];
  char* Kl  = smem;          // 8192 B: K [key][d]  (bf16, XOR-swizzled rows)
  char* KTl = smem + 8192;   // 8192 B: K^T [d][key]
  char* Pl  = smem + 16384;  // 4 x 2048 B: per-wave P [q][key]

  const int t  = threadIdx.x;
  const int w  = t >> 6, l = t & 63;
  const int lm = l & 15, lg = l >> 4;
  const int b  = blockIdx.x >> 5;
  const int p  = blockIdx.x & 31;
  const size_t bbase = (size_t)b * TT;
  char* Pw  = Pl + w * 2048;
  char* OtW = smem + w * 4096;  // epilogue scratch overlays Kl/KTl

  for (int pass = 0; pass < 2; ++pass) {
    const int tile  = pass ? (63 - p) : p;
    const int qbase = tile * 64;
    const int qg    = qbase + w * 16 + lm;  // this lane's q column

    // Q fragment (B-operand), 2 k-steps of 32
    s16x8 qf[2];
#pragma unroll
    for (int s = 0; s < 2; ++s)
      qf[s] = *(const s16x8*)(Qg + (size_t)(bbase + qbase + w * 16 + lm) * DD + s * 32 + 8 * lg);

    float m = -INFINITY, lsum = 0.f;
    f32x4 oacc[4];
#pragma unroll
    for (int i = 0; i < 4; ++i) oacc[i] = (f32x4)0.f;

    for (int ch = 0; ch <= tile; ++ch) {
      const int kb = ch * 64;
      __syncthreads();
      // ---- stage K chunk (64 keys x 64 d): row-major + transposed, swizzled
#pragma unroll
      for (int i = 0; i < 2; ++i) {
        const int flat = t + i * 256;
        const int row = flat >> 3, dblk = flat & 7;
        union { uint4 u4; ushort us[8]; } v;
        v.u4 = *(const uint4*)(Kg + (size_t)(bbase + kb + row) * DD + dblk * 8);
        *(uint4*)(Kl + row * 128 + ((dblk * 16) ^ ((row & 7) << 4))) = v.u4;
#pragma unroll
        for (int w8 = 0; w8 < 8; ++w8) {
          const int j = (w8 + t) & 7;           // lane-rotated -> no bank pileup
          const int d = dblk * 8 + j;
          *(ushort*)(KTl + d * 128 + ((row * 2) ^ (j << 4))) = v.us[j];
        }
      }
      __syncthreads();

      // ---- S^T = K . Q   (4 key-tiles x 2 k-steps)
      f32x4 sacc[4];
#pragma unroll
      for (int kt = 0; kt < 4; ++kt) sacc[kt] = (f32x4)0.f;
#pragma unroll
      for (int ks = 0; ks < 2; ++ks) {
#pragma unroll
        for (int kt = 0; kt < 4; ++kt) {
          const int key = kt * 16 + lm;
          s16x8 af = *(const s16x8*)(Kl + key * 128 + ((ks * 64 + lg * 16) ^ ((key & 7) << 4)));
          sacc[kt] = __builtin_amdgcn_mfma_f32_16x16x32_bf16(af, qf[ks], sacc[kt], 0, 0, 0);
        }
      }
      // ---- causal mask (diagonal chunk only)
      if (ch == tile) {
#pragma unroll
        for (int kt = 0; kt < 4; ++kt) {
          const int keyb = kb + kt * 16 + 4 * lg;
#pragma unroll
          for (int r = 0; r < 4; ++r)
            if (keyb + r > qg) sacc[kt][r] = -INFINITY;
        }
      }
      // ---- online softmax (lane-local per q; reduce across lg groups)
      float mc = -INFINITY;
#pragma unroll
      for (int kt = 0; kt < 4; ++kt)
#pragma unroll
        for (int r = 0; r < 4; ++r) mc = fmaxf(mc, sacc[kt][r]);
      mc = fmaxf(mc, __shfl_xor(mc, 16));
      mc = fmaxf(mc, __shfl_xor(mc, 32));
      const float mnew = fmaxf(m, mc);
      const float corr = __expf(m - mnew);  // first chunk: exp(-inf)=0
      float ps = 0.f;
#pragma unroll
      for (int kt = 0; kt < 4; ++kt) {
        float pv[4];
#pragma unroll
        for (int r = 0; r < 4; ++r) { pv[r] = __expf(sacc[kt][r] - mnew); ps += pv[r]; }
        const int key0 = kt * 16 + 4 * lg;
        const uint pk01 = (uint)f2bf(pv[0]) | ((uint)f2bf(pv[1]) << 16);
        const uint pk23 = (uint)f2bf(pv[2]) | ((uint)f2bf(pv[3]) << 16);
        *(uint*)(Pw + lm * 128 + (((key0) * 2)     ^ ((lm & 7) << 4))) = pk01;
        *(uint*)(Pw + lm * 128 + (((key0 + 2) * 2) ^ ((lm & 7) << 4))) = pk23;
      }
      ps += __shfl_xor(ps, 16);
      ps += __shfl_xor(ps, 32);
      lsum = lsum * corr + ps;
      m = mnew;
#pragma unroll
      for (int i = 0; i < 4; ++i) oacc[i] *= corr;

      // ---- O^T += V^T . P^T   (V == K; 4 d-tiles x 2 k-steps)
#pragma unroll
      for (int ks = 0; ks < 2; ++ks) {
        s16x8 pf = *(const s16x8*)(Pw + lm * 128 + ((ks * 64 + lg * 16) ^ ((lm & 7) << 4)));
#pragma unroll
        for (int dt = 0; dt < 4; ++dt) {
          const int d = dt * 16 + lm;
          s16x8 vf = *(const s16x8*)(KTl + d * 128 + ((ks * 64 + lg * 16) ^ ((d & 7) << 4)));
          oacc[dt] = __builtin_amdgcn_mfma_f32_16x16x32_bf16(vf, pf, oacc[dt], 0, 0, 0);
        }
      }
    }

    // ---- epilogue: O^T -> LDS transpose -> coalesced float4 stores
    const float inv = 1.f / lsum;
    __syncthreads();  // all waves done reading K/KT before overwrite
#pragma unroll
    for (int dt = 0; dt < 4; ++dt)
#pragma unroll
      for (int r = 0; r < 4; ++r) {
        const int d = dt * 16 + 4 * lg + r;
        *(float*)(OtW + lm * 256 + ((d * 4) ^ ((lm & 7) << 4))) = oacc[dt][r] * inv;
      }
#pragma unroll
    for (int i = 0; i < 4; ++i) {
      const int q  = l >> 2;
      const int d0 = i * 16 + (l & 3) * 4;
      f32x4 ov = *(const f32x4*)(OtW + q * 256 + ((d0 * 4) ^ ((q & 7) << 4)));
      *(f32x4*)(O + (size_t)(bbase + qbase + w * 16 + q) * DD + d0) = ov;
    }
  }
}

extern "C" void kernel_launch(void* const* d_in, const int* in_sizes, int n_in,
                              void* d_out, int out_size, void* d_ws, size_t ws_size,
                              hipStream_t stream) {
  const float* x  = (const float*)d_in[0];
  const float* wq = (const float*)d_in[1];
  const float* wk = (const float*)d_in[2];
  float* out = (float*)d_out;

  const size_t rows = (size_t)BB * TT;  // 32768
  ushort* Qbuf = (ushort*)d_ws;
  ushort* Kbuf = Qbuf + rows * DD;      // 4 MB each

  proj_kernel<<<dim3(rows / 64), dim3(256), 0, stream>>>(x, wq, wk, Qbuf, Kbuf);
  attn_kernel<<<dim3(BB * 32), dim3(256), 0, stream>>>(Qbuf, Kbuf, out);
}

// Round 3
// 86.488 us; speedup vs baseline: 20.4247x; 2.8417x over previous
//
#include <hip/hip_runtime.h>
#include <math.h>

#define BB 8
#define TT 4096
#define NE 512
#define DD 64

using f32x4 = __attribute__((ext_vector_type(4))) float;
using s16x8 = __attribute__((ext_vector_type(8))) short;

__device__ __forceinline__ ushort f2bf(float f) {
  uint u = __builtin_bit_cast(uint, f);
  u += 0x7fffu + ((u >> 16) & 1u);
  return (ushort)(u >> 16);
}
__device__ __forceinline__ uint pack2(float a, float b) {
  return (uint)f2bf(a) | ((uint)f2bf(b) << 16);
}

#define KTSWZ(d) ((((d) ^ ((d) >> 3)) & 7) << 4)

// ---------------- prep: WT[col][k] bf16, col<64 = wq*0.125, col>=64 = wk -----
__global__ __launch_bounds__(256) void prep_kernel(
    const float* __restrict__ wq, const float* __restrict__ wk,
    ushort* __restrict__ WT) {
  const int i = blockIdx.x * 256 + threadIdx.x;  // 65536
  const int col = i & 127, k = i >> 7;
  const float v = (col < DD) ? wq[(size_t)k * DD + col] * 0.125f
                             : wk[(size_t)k * DD + (col - DD)];
  WT[(size_t)col * NE + k] = f2bf(v);
}

// ---------------- proj: bf16 MFMA GEMM, out = x @ [wq*0.125 | wk] ------------
// 512 blocks x 256 thr (4 waves 2x2). Tile 64 rows x 128 cols, K-step 64,
// register-prefetched staging (x fp32 -> bf16 in flight).
__global__ __launch_bounds__(256) void proj_kernel(
    const float* __restrict__ x, const ushort* __restrict__ WT,
    ushort* __restrict__ Qo, ushort* __restrict__ Ko) {
  __shared__ __align__(16) char smem[24576];
  char* As = smem;          // [64 rows][128B] swizzled
  char* Bs = smem + 8192;   // [128 cols][128B] swizzled (WT tile)
  const int t = threadIdx.x;
  const int w = t >> 6, l = t & 63;
  const int lm = l & 15, lg = l >> 4;
  const int wr = w >> 1, wc = w & 1;
  const size_t rbase = (size_t)blockIdx.x * 64;

  const int arow = t >> 2, akq = (t & 3) * 16;  // A: 16 fp32 per thread
  const int bcol = t >> 1, bkh = (t & 1) * 32;  // B: 32 bf16 per thread

  f32x4 acc[2][4];
#pragma unroll
  for (int mt = 0; mt < 2; ++mt)
#pragma unroll
    for (int nt = 0; nt < 4; ++nt) acc[mt][nt] = (f32x4)0.f;

  float4 xa0, xa1, xa2, xa3;
  uint4 wb0, wb1, wb2, wb3;
  {
    const float* xp = x + (rbase + arow) * NE + akq;
    xa0 = *(const float4*)(xp + 0);  xa1 = *(const float4*)(xp + 4);
    xa2 = *(const float4*)(xp + 8);  xa3 = *(const float4*)(xp + 12);
    const ushort* wp = WT + (size_t)bcol * NE + bkh;
    wb0 = *(const uint4*)(wp + 0);   wb1 = *(const uint4*)(wp + 8);
    wb2 = *(const uint4*)(wp + 16);  wb3 = *(const uint4*)(wp + 24);
  }

  for (int kstep = 0; kstep < NE; kstep += 64) {
    __syncthreads();
    {
      uint4 a0, a1;
      a0.x = pack2(xa0.x, xa0.y); a0.y = pack2(xa0.z, xa0.w);
      a0.z = pack2(xa1.x, xa1.y); a0.w = pack2(xa1.z, xa1.w);
      a1.x = pack2(xa2.x, xa2.y); a1.y = pack2(xa2.z, xa2.w);
      a1.z = pack2(xa3.x, xa3.y); a1.w = pack2(xa3.z, xa3.w);
      const int swa = (arow & 7) << 4;
      *(uint4*)(As + arow * 128 + ((akq * 2) ^ swa)) = a0;
      *(uint4*)(As + arow * 128 + ((akq * 2 + 16) ^ swa)) = a1;
      const int swb = (bcol & 7) << 4;
      *(uint4*)(Bs + bcol * 128 + ((bkh * 2) ^ swb)) = wb0;
      *(uint4*)(Bs + bcol * 128 + ((bkh * 2 + 16) ^ swb)) = wb1;
      *(uint4*)(Bs + bcol * 128 + ((bkh * 2 + 32) ^ swb)) = wb2;
      *(uint4*)(Bs + bcol * 128 + ((bkh * 2 + 48) ^ swb)) = wb3;
    }
    __syncthreads();
    {
      const int kn = (kstep + 64 < NE) ? kstep + 64 : kstep;
      const float* xp = x + (rbase + arow) * NE + kn + akq;
      xa0 = *(const float4*)(xp + 0);  xa1 = *(const float4*)(xp + 4);
      xa2 = *(const float4*)(xp + 8);  xa3 = *(const float4*)(xp + 12);
      const ushort* wp = WT + (size_t)bcol * NE + kn + bkh;
      wb0 = *(const uint4*)(wp + 0);   wb1 = *(const uint4*)(wp + 8);
      wb2 = *(const uint4*)(wp + 16);  wb3 = *(const uint4*)(wp + 24);
    }
#pragma unroll
    for (int ks = 0; ks < 2; ++ks) {
      s16x8 af[2];
#pragma unroll
      for (int mt = 0; mt < 2; ++mt) {
        const int row = wr * 32 + mt * 16 + lm;
        af[mt] = *(const s16x8*)(As + row * 128 + ((ks * 64 + lg * 16) ^ ((row & 7) << 4)));
      }
#pragma unroll
      for (int nt = 0; nt < 4; ++nt) {
        const int col = wc * 64 + nt * 16 + lm;
        s16x8 bf = *(const s16x8*)(Bs + col * 128 + ((ks * 64 + lg * 16) ^ ((col & 7) << 4)));
#pragma unroll
        for (int mt = 0; mt < 2; ++mt)
          acc[mt][nt] = __builtin_amdgcn_mfma_f32_16x16x32_bf16(af[mt], bf, acc[mt][nt], 0, 0, 0);
      }
    }
  }
#pragma unroll
  for (int nt = 0; nt < 4; ++nt) {
    const int col = wc * 64 + nt * 16 + lm;
    ushort* dst = (col < DD) ? Qo : Ko;
    const int c = col & 63;
#pragma unroll
    for (int mt = 0; mt < 2; ++mt)
#pragma unroll
      for (int r = 0; r < 4; ++r) {
        const size_t row = rbase + wr * 32 + mt * 16 + 4 * lg + r;
        dst[row * DD + c] = f2bf(acc[mt][nt][r]);
      }
  }
}

// ---------------- MFMA flash attention, split-K partials ---------------------
// Block: 4 waves x 32 q = 128-q tile; pair (t, 31-t) = 66 chunks, split S ways.
// Writes unnormalized partial O + (m,l) when S>1; direct output when S==1.
__global__ __launch_bounds__(256) void attn_kernel(
    const ushort* __restrict__ Qg, const ushort* __restrict__ Kg,
    float* __restrict__ PO, float* __restrict__ ML, float* __restrict__ Od,
    int S) {
  __shared__ __align__(16) char smem[32768];
  char* Kl  = smem;           // 8KB [64 keys][128B] swizzled
  char* KTl = smem + 8192;    // 8KB [64 d][128B]   swizzled (K^T == V^T)
  char* Pl  = smem + 16384;   // 4 x 4KB per-wave P [32 q][128B]

  const int t = threadIdx.x;
  const int w = t >> 6, l = t & 63;
  const int lm = l & 15, lg = l >> 4;
  int idx = blockIdx.x;
  const int s = idx % S; idx /= S;
  const int pr = idx & 15;
  const int b = idx >> 4;
  const size_t bbase = (size_t)b * TT;
  char* Pw = Pl + w * 4096;

  const int rp = t >> 3;    // 0..31 key rowpair
  const int dblk = t & 7;   // 0..7

  for (int pass = 0; pass < 2; ++pass) {
    const int tile = pass ? (31 - pr) : pr;
    const int qwb = tile * 128 + w * 32;     // wave q base (within batch)
    const int nc = 2 * tile + 2;
    const int c0 = (s * nc) / S, c1 = ((s + 1) * nc) / S;

    s16x8 qf[2][2];
#pragma unroll
    for (int qi = 0; qi < 2; ++qi)
#pragma unroll
      for (int ks = 0; ks < 2; ++ks)
        qf[qi][ks] = *(const s16x8*)(Qg + (bbase + qwb + qi * 16 + lm) * DD + ks * 32 + lg * 8);

    float mrun[2] = {-1e30f, -1e30f};
    float lrun[2] = {0.f, 0.f};
    f32x4 oacc[2][4];
#pragma unroll
    for (int qi = 0; qi < 2; ++qi)
#pragma unroll
      for (int dt = 0; dt < 4; ++dt) oacc[qi][dt] = (f32x4)0.f;

    uint4 ra, rb;
    {
      const int cc = (c0 < nc) ? c0 : nc - 1;
      const ushort* src = Kg + (bbase + cc * 64 + 2 * rp) * DD + dblk * 8;
      ra = *(const uint4*)src;
      rb = *(const uint4*)(src + DD);
    }

    for (int c = c0; c < c1; ++c) {
      const int kb = c * 64;
      __syncthreads();
      {  // stage chunk c from prefetched regs
        const int r0 = 2 * rp, r1 = r0 + 1;
        *(uint4*)(Kl + r0 * 128 + ((dblk * 16) ^ ((r0 & 7) << 4))) = ra;
        *(uint4*)(Kl + r1 * 128 + ((dblk * 16) ^ ((r1 & 7) << 4))) = rb;
        union { uint4 u; ushort us[8]; } ua, ub;
        ua.u = ra; ub.u = rb;
#pragma unroll
        for (int j = 0; j < 8; ++j) {
          const int d = dblk * 8 + j;
          const uint val = (uint)ua.us[j] | ((uint)ub.us[j] << 16);
          *(uint*)(KTl + d * 128 + ((rp * 4) ^ KTSWZ(d))) = val;
        }
      }
      __syncthreads();
      {  // prefetch chunk c+1 (clamped to valid range)
        const int cn = (c + 1 < c1) ? (c + 1) : (nc - 1);
        const ushort* src = Kg + (bbase + cn * 64 + 2 * rp) * DD + dblk * 8;
        ra = *(const uint4*)src;
        rb = *(const uint4*)(src + DD);
      }

      const bool act0 = (kb <= qwb + 15);
      const bool act1 = (kb <= qwb + 31);
      if (!act1) continue;  // wave fully masked this chunk (barriers at loop top)

      // ---- S^T = K . Q  (af shared across both q-frags)
      f32x4 sa[2][4];
#pragma unroll
      for (int qi = 0; qi < 2; ++qi)
#pragma unroll
        for (int kt = 0; kt < 4; ++kt) sa[qi][kt] = (f32x4)0.f;
#pragma unroll
      for (int ks = 0; ks < 2; ++ks) {
#pragma unroll
        for (int kt = 0; kt < 4; ++kt) {
          const int key = kt * 16 + lm;
          s16x8 af = *(const s16x8*)(Kl + key * 128 + ((ks * 64 + lg * 16) ^ ((key & 7) << 4)));
          if (act0)
            sa[0][kt] = __builtin_amdgcn_mfma_f32_16x16x32_bf16(af, qf[0][ks], sa[0][kt], 0, 0, 0);
          sa[1][kt] = __builtin_amdgcn_mfma_f32_16x16x32_bf16(af, qf[1][ks], sa[1][kt], 0, 0, 0);
        }
      }

      // ---- mask + online softmax + P pack (per q-frag)
#pragma unroll
      for (int qi = 0; qi < 2; ++qi) {
        const bool act = qi ? act1 : act0;
        if (!act) continue;
        const int qg = qwb + qi * 16 + lm;
        if (kb + 63 > qwb + qi * 16) {
#pragma unroll
          for (int kt = 0; kt < 4; ++kt) {
            const int key0 = kb + kt * 16 + 4 * lg;
#pragma unroll
            for (int r = 0; r < 4; ++r)
              if (key0 + r > qg) sa[qi][kt][r] = -1e30f;
          }
        }
        float mc = -1e30f;
#pragma unroll
        for (int kt = 0; kt < 4; ++kt)
#pragma unroll
          for (int r = 0; r < 4; ++r) mc = fmaxf(mc, sa[qi][kt][r]);
        mc = fmaxf(mc, __shfl_xor(mc, 16));
        mc = fmaxf(mc, __shfl_xor(mc, 32));
        const float mn = fmaxf(mrun[qi], mc);
        const float corr = __expf(mrun[qi] - mn);
        mrun[qi] = mn;
        float ps = 0.f;
        const int prow = qi * 16 + lm;
        const int swp = (lm & 7) << 4;
#pragma unroll
        for (int kt = 0; kt < 4; ++kt) {
          float pv[4];
#pragma unroll
          for (int r = 0; r < 4; ++r) {
            const float sv = sa[qi][kt][r];
            pv[r] = (sv > -0.5e30f) ? __expf(sv - mn) : 0.f;  // masked -> exactly 0
            ps += pv[r];
          }
          const int off = kt * 32 + lg * 8;
          *(uint*)(Pw + prow * 128 + (off ^ swp)) = pack2(pv[0], pv[1]);
          *(uint*)(Pw + prow * 128 + ((off + 4) ^ swp)) = pack2(pv[2], pv[3]);
        }
        ps += __shfl_xor(ps, 16);
        ps += __shfl_xor(ps, 32);
        lrun[qi] = lrun[qi] * corr + ps;
#pragma unroll
        for (int dt = 0; dt < 4; ++dt) oacc[qi][dt] *= corr;
      }

      // ---- O^T += V^T . P^T  (V == K; vf shared across q-frags)
#pragma unroll
      for (int ks = 0; ks < 2; ++ks) {
        s16x8 pf0 = {}, pf1 = {};
        if (act0) pf0 = *(const s16x8*)(Pw + lm * 128 + ((ks * 64 + lg * 16) ^ ((lm & 7) << 4)));
        if (act1) pf1 = *(const s16x8*)(Pw + (16 + lm) * 128 + ((ks * 64 + lg * 16) ^ ((lm & 7) << 4)));
#pragma unroll
        for (int dt = 0; dt < 4; ++dt) {
          const int d = dt * 16 + lm;
          s16x8 vf = *(const s16x8*)(KTl + d * 128 + ((ks * 64 + lg * 16) ^ KTSWZ(d)));
          if (act0) oacc[0][dt] = __builtin_amdgcn_mfma_f32_16x16x32_bf16(vf, pf0, oacc[0][dt], 0, 0, 0);
          if (act1) oacc[1][dt] = __builtin_amdgcn_mfma_f32_16x16x32_bf16(vf, pf1, oacc[1][dt], 0, 0, 0);
        }
      }
    }

    // ---- epilogue: direct output (S==1) or unnormalized partials
    if (S == 1) {
#pragma unroll
      for (int qi = 0; qi < 2; ++qi) {
        const size_t qrow = bbase + qwb + qi * 16 + lm;
        const float inv = 1.f / lrun[qi];
#pragma unroll
        for (int dt = 0; dt < 4; ++dt) {
          f32x4 v = oacc[qi][dt] * inv;
          *(f32x4*)(Od + qrow * DD + dt * 16 + 4 * lg) = v;
        }
      }
    } else {
#pragma unroll
      for (int qi = 0; qi < 2; ++qi) {
        const size_t prow = ((size_t)s * BB + b) * TT + qwb + qi * 16 + lm;
#pragma unroll
        for (int dt = 0; dt < 4; ++dt)
          *(f32x4*)(PO + prow * DD + dt * 16 + 4 * lg) = oacc[qi][dt];
        if (lg == 0) {
          ML[prow * 2] = mrun[qi];
          ML[prow * 2 + 1] = lrun[qi];
        }
      }
    }
  }
}

// ---------------- merge S partials -------------------------------------------
__global__ __launch_bounds__(256) void merge_kernel(
    const float* __restrict__ PO, const float* __restrict__ ML,
    float* __restrict__ O, int S) {
  const int flat = blockIdx.x * 256 + threadIdx.x;
  const int q = flat >> 4;          // global row 0..32767
  const int d0 = (flat & 15) * 4;
  float mt = -1e30f;
  for (int s = 0; s < S; ++s)
    mt = fmaxf(mt, ML[((size_t)s * BB * TT + q) * 2]);
  float lsum = 0.f;
  f32x4 acc = (f32x4)0.f;
  for (int s = 0; s < S; ++s) {
    const size_t prow = (size_t)s * BB * TT + q;
    const float m = ML[prow * 2], lv = ML[prow * 2 + 1];
    const float wgt = __expf(m - mt);
    lsum = fmaf(wgt, lv, lsum);
    const f32x4 po = *(const f32x4*)(PO + prow * DD + d0);
#pragma unroll
    for (int i = 0; i < 4; ++i) acc[i] = fmaf(wgt, po[i], acc[i]);
  }
  const float inv = 1.f / lsum;
#pragma unroll
  for (int i = 0; i < 4; ++i) acc[i] *= inv;
  *(f32x4*)(O + (size_t)q * DD + d0) = acc;
}

extern "C" void kernel_launch(void* const* d_in, const int* in_sizes, int n_in,
                              void* d_out, int out_size, void* d_ws, size_t ws_size,
                              hipStream_t stream) {
  const float* x  = (const float*)d_in[0];
  const float* wq = (const float*)d_in[1];
  const float* wk = (const float*)d_in[2];
  // d_in[3] (w_v) unused: reference computes v with w_k.
  float* out = (float*)d_out;

  const size_t rows = (size_t)BB * TT;         // 32768
  ushort* WT   = (ushort*)d_ws;                // 128 KB
  ushort* Qbuf = WT + (size_t)128 * NE;        // 4 MB
  ushort* Kbuf = Qbuf + rows * DD;             // 4 MB
  char*  after = (char*)(Kbuf + rows * DD);
  const size_t used = (size_t)(after - (char*)d_ws);
  const size_t per  = rows * 2 * 4 + rows * DD * 4;  // ML + PO per split
  int S = 1;
  if (used + 4 * per <= ws_size) S = 4;
  else if (used + 2 * per <= ws_size) S = 2;
  float* ML = (float*)after;
  float* PO = ML + (size_t)S * rows * 2;

  prep_kernel<<<dim3(256), dim3(256), 0, stream>>>(wq, wk, WT);
  proj_kernel<<<dim3(512), dim3(256), 0, stream>>>(x, WT, Qbuf, Kbuf);
  attn_kernel<<<dim3(BB * 16 * S), dim3(256), 0, stream>>>(Qbuf, Kbuf, PO, ML, out, S);
  if (S > 1)
    merge_kernel<<<dim3(2048), dim3(256), 0, stream>>>(PO, ML, out, S);
}